// Round 7
// baseline (101.654 us; speedup 1.0000x reference)
//
#include <hip/hip_runtime.h>

typedef float f4 __attribute__((ext_vector_type(4)));

static constexpr int B = 16, S = 4096, H = 1024, W = 1024;
static constexpr int NC = 128;           // number of S-chunks
static constexpr int CS = S / NC;        // 32 rows per chunk
static constexpr int LOG2_CS = 5;
static constexpr int BMW = S / 32;       // 128 bitmap words per batch (1 per chunk)

// ---------------------------------------------------------------------------
// Kernel 1: boundary bitmap via LDS. One block per batch (16 blocks, ~2 us).
// Keeps k_prefix completely barrier-free so it streams from instruction 0.
// ---------------------------------------------------------------------------
__global__ void __launch_bounds__(256)
k_bitset(const int* __restrict__ widx, const int* __restrict__ mwl,
         unsigned* __restrict__ bm) {
    __shared__ unsigned lbm[BMW];
    int b = blockIdx.x, t = threadIdx.x;
    for (int i = t; i < BMW; i += 256) lbm[i] = 0u;
    __syncthreads();
    int nv = mwl[b];
    for (int w = t; w < W; w += 256) {
        if (w < nv) {
            int2 se = *(const int2*)(widx + ((size_t)b * W + w) * 2);
            atomicOr(&lbm[se.y >> 5], 1u << (se.y & 31));
            if (se.x > 0) {
                int sm = se.x - 1;
                atomicOr(&lbm[sm >> 5], 1u << (sm & 31));
            }
        }
    }
    __syncthreads();
    for (int i = t; i < BMW; i += 256) bm[b * BMW + i] = lbm[i];
}

// ---------------------------------------------------------------------------
// Kernel 2: chunk-local inclusive prefix along S; NO LDS, NO barrier.
// bm word is a wave-uniform scalar load; hs loads issue immediately.
// Stores ONLY flagged rows of L; chunk totals stored densely to CT.
// grid = B*NC = 2048 blocks (8/CU, 32 waves/CU max occupancy).
// ---------------------------------------------------------------------------
__global__ void __launch_bounds__(256)
k_prefix(const float* __restrict__ hs, const unsigned* __restrict__ bm,
         float* __restrict__ L, float* __restrict__ CT) {
    const int c = blockIdx.x % NC;
    const int b = blockIdx.x / NC;
    const unsigned bw = bm[b * BMW + c];     // one word per 32-row chunk
    const int col = threadIdx.x * 4;
    size_t rowbase = ((size_t)b * S + (size_t)c * CS) * H + col;
    f4 acc = {0.f, 0.f, 0.f, 0.f};
#pragma unroll 16
    for (int s = 0; s < CS; ++s) {
        f4 v = __builtin_nontemporal_load((const f4*)(hs + rowbase + (size_t)s * H));
        acc += v;
        if ((bw >> s) & 1u)
            *(f4*)(L + rowbase + (size_t)s * H) = acc;
    }
    *(f4*)(CT + ((size_t)b * NC + c) * H + col) = acc;
}

// ---------------------------------------------------------------------------
// Kernel 3: in-place exclusive scan of chunk totals along c.
// grid = B*(H/256) = 64 blocks.
// ---------------------------------------------------------------------------
__global__ void __launch_bounds__(256)
k_coarse(float* __restrict__ CT) {
    int hq = blockIdx.x % (H / 256);
    int b  = blockIdx.x / (H / 256);
    int h  = hq * 256 + threadIdx.x;
    float acc = 0.f;
#pragma unroll 8
    for (int c = 0; c < NC; ++c) {
        size_t idx = ((size_t)b * NC + c) * H + h;
        float v = CT[idx];
        CT[idx] = acc;
        acc += v;
    }
}

// ---------------------------------------------------------------------------
// Kernel 4: gather. One wave per word; 4 words per 256-thread block.
// sum(start..end) = (L[end]+CT[c_end]) - (L[start-1]+CT[c_sm]).
// NT stores for out (never re-read). All branches wave-uniform.
// ---------------------------------------------------------------------------
__global__ void __launch_bounds__(256)
k_gather(const float* __restrict__ L, const float* __restrict__ CT,
         const int* __restrict__ widx, const int* __restrict__ mwl,
         float* __restrict__ out, float* __restrict__ mask) {
    int t = threadIdx.x;
    int wid = t >> 6, lane = t & 63;
    int word = blockIdx.x * 4 + wid;
    int b = word / W, w = word % W;
    size_t orow = (size_t)word * H;

    bool valid = (w < mwl[b]);
    if (lane == 0) mask[word] = valid ? 1.0f : 0.0f;

    if (!valid) {
        f4 z = {0.f, 0.f, 0.f, 0.f};
#pragma unroll
        for (int k = 0; k < 4; ++k)
            __builtin_nontemporal_store(z, (f4*)(out + orow + k * 256 + lane * 4));
        return;
    }

    int start = widx[(size_t)word * 2 + 0];
    int end   = widx[(size_t)word * 2 + 1];
    float inv = 1.0f / (float)(end - start + 1);
    int ce = end >> LOG2_CS;
    const float* Le = L  + ((size_t)b * S + end) * H;
    const float* Ce = CT + ((size_t)b * NC + ce) * H;
    bool has_s = (start > 0);
    const float* Ls = Le; const float* Cs = Ce;
    if (has_s) {
        int sm = start - 1, cs = sm >> LOG2_CS;
        Ls = L  + ((size_t)b * S + sm) * H;
        Cs = CT + ((size_t)b * NC + cs) * H;
    }

#pragma unroll
    for (int k = 0; k < 4; ++k) {
        int off = k * 256 + lane * 4;
        f4 e  = *(const f4*)(Le + off);
        f4 ct = *(const f4*)(Ce + off);
        f4 ssum = e + ct;
        if (has_s) {
            f4 s4 = *(const f4*)(Ls + off);
            f4 c4 = *(const f4*)(Cs + off);
            ssum -= s4 + c4;
        }
        f4 o = ssum * inv;
        __builtin_nontemporal_store(o, (f4*)(out + orow + off));
    }
}

// ---------------------------------------------------------------------------
// Fallback: direct summation if workspace is too small. Correct but slow.
// ---------------------------------------------------------------------------
__global__ void k_direct(const float* __restrict__ hs, const int* __restrict__ widx,
                         const int* __restrict__ mwl, float* __restrict__ out,
                         float* __restrict__ mask) {
    int w = blockIdx.x % W;
    int b = blockIdx.x / W;
    int t = threadIdx.x;
    bool valid = (w < mwl[b]);
    size_t orow = ((size_t)b * W + w) * H;
    if (t == 0) mask[(size_t)b * W + w] = valid ? 1.0f : 0.0f;

    f4 acc = {0.f, 0.f, 0.f, 0.f};
    if (valid) {
        int start = widx[((size_t)b * W + w) * 2 + 0];
        int end   = widx[((size_t)b * W + w) * 2 + 1];
        float inv = 1.0f / (float)(end - start + 1);
        for (int s = start; s <= end; ++s) {
            f4 v = *(const f4*)(hs + ((size_t)b * S + s) * H + (size_t)t * 4);
            acc += v;
        }
        acc *= inv;
    }
    *(f4*)(out + orow + (size_t)t * 4) = acc;
}

extern "C" void kernel_launch(void* const* d_in, const int* in_sizes, int n_in,
                              void* d_out, int out_size, void* d_ws, size_t ws_size,
                              hipStream_t stream) {
    const float* hs  = (const float*)d_in[0];
    const int*  widx = (const int*)d_in[1];
    const int*  mwl  = (const int*)d_in[2];
    float* out  = (float*)d_out;
    float* mask = out + (size_t)B * W * H;   // masks follow embeddings, flat

    const size_t Lbytes  = (size_t)B * S * H * sizeof(float);      // 256 MiB
    const size_t CTbytes = (size_t)B * NC * H * sizeof(float);     // 8 MiB
    const size_t BMbytes = (size_t)B * BMW * sizeof(unsigned);     // 8 KiB

    if (ws_size >= Lbytes + CTbytes + BMbytes) {
        float* L     = (float*)d_ws;
        float* CT    = (float*)((char*)d_ws + Lbytes);
        unsigned* bm = (unsigned*)((char*)d_ws + Lbytes + CTbytes);

        hipLaunchKernelGGL(k_bitset, dim3(B),               dim3(256), 0, stream, widx, mwl, bm);
        hipLaunchKernelGGL(k_prefix, dim3(B * NC),          dim3(256), 0, stream, hs, bm, L, CT);
        hipLaunchKernelGGL(k_coarse, dim3(B * (H / 256)),   dim3(256), 0, stream, CT);
        hipLaunchKernelGGL(k_gather, dim3(B * W / 4),       dim3(256), 0, stream,
                           L, CT, widx, mwl, out, mask);
    } else {
        hipLaunchKernelGGL(k_direct, dim3(B * W), dim3(256), 0, stream, hs, widx, mwl, out, mask);
    }
}

// Round 8
// 100.242 us; speedup vs baseline: 1.0141x; 1.0141x over previous
//
#include <hip/hip_runtime.h>

typedef float f4 __attribute__((ext_vector_type(4)));

static constexpr int B = 16, S = 4096, H = 1024, W = 1024;
static constexpr int NC = 128;           // number of S-chunks
static constexpr int CS = S / NC;        // 32 rows per chunk
static constexpr int LOG2_CS = 5;

// ---------------------------------------------------------------------------
// Kernel 1: chunk-local inclusive prefix along S with INLINE boundary-mask
// derivation (proven round-6 structure: 3 dispatches total). Stores ONLY
// flagged rows of L; chunk totals stored densely to CT.
// grid = B*NC = 2048 blocks (8/CU, 32 waves/CU). 256 thr x f4 covers H=1024.
// ---------------------------------------------------------------------------
__global__ void __launch_bounds__(256)
k_prefix(const float* __restrict__ hs, const int* __restrict__ widx,
         const int* __restrict__ mwl, float* __restrict__ L,
         float* __restrict__ CT) {
    const int c = blockIdx.x % NC;
    const int b = blockIdx.x / NC;
    const int t = threadIdx.x;

    // --- derive this chunk's 32-bit boundary mask from widx ---
    __shared__ unsigned sbw;
    if (t == 0) sbw = 0u;
    __syncthreads();
    const int nv = mwl[b];
    const int lo = c * CS;
    unsigned mybits = 0u;
#pragma unroll
    for (int w = t; w < W; w += 256) {
        if (w < nv) {
            int2 se = *(const int2*)(widx + ((size_t)b * W + w) * 2);
            int e  = se.y - lo;
            int sm = se.x - 1 - lo;
            if ((unsigned)e  < (unsigned)CS) mybits |= 1u << e;
            if ((unsigned)sm < (unsigned)CS) mybits |= 1u << sm;
        }
    }
    if (mybits) atomicOr(&sbw, mybits);
    __syncthreads();
    const unsigned bw = sbw;

    // --- streaming scan: NT loads of hs, sparse plain stores of L ---
    const int col = t * 4;
    size_t rowbase = ((size_t)b * S + (size_t)lo) * H + col;
    f4 acc = {0.f, 0.f, 0.f, 0.f};
#pragma unroll 8
    for (int s = 0; s < CS; ++s) {
        f4 v = __builtin_nontemporal_load((const f4*)(hs + rowbase + (size_t)s * H));
        acc += v;
        if ((bw >> s) & 1u)
            *(f4*)(L + rowbase + (size_t)s * H) = acc;
    }
    *(f4*)(CT + ((size_t)b * NC + c) * H + col) = acc;
}

// ---------------------------------------------------------------------------
// Kernel 2: in-place exclusive scan of chunk totals along c.
// grid = B*(H/256) = 64 blocks.
// ---------------------------------------------------------------------------
__global__ void __launch_bounds__(256)
k_coarse(float* __restrict__ CT) {
    int hq = blockIdx.x % (H / 256);
    int b  = blockIdx.x / (H / 256);
    int h  = hq * 256 + threadIdx.x;
    float acc = 0.f;
#pragma unroll 8
    for (int c = 0; c < NC; ++c) {
        size_t idx = ((size_t)b * NC + c) * H + h;
        float v = CT[idx];
        CT[idx] = acc;
        acc += v;
    }
}

// ---------------------------------------------------------------------------
// Kernel 3: gather. One wave per word; 8 words per 256-thread block
// (grid = B*W/8 = 2048) to amortize block prologue. All branches
// wave-uniform. NT stores for out (never re-read).
// ---------------------------------------------------------------------------
__global__ void __launch_bounds__(256)
k_gather(const float* __restrict__ L, const float* __restrict__ CT,
         const int* __restrict__ widx, const int* __restrict__ mwl,
         float* __restrict__ out, float* __restrict__ mask) {
    int t = threadIdx.x;
    int wid = t >> 6, lane = t & 63;

#pragma unroll
    for (int i = 0; i < 2; ++i) {
        int word = blockIdx.x * 8 + i * 4 + wid;
        int b = word / W, w = word % W;
        size_t orow = (size_t)word * H;

        bool valid = (w < mwl[b]);
        if (lane == 0) mask[word] = valid ? 1.0f : 0.0f;

        if (!valid) {
            f4 z = {0.f, 0.f, 0.f, 0.f};
#pragma unroll
            for (int k = 0; k < 4; ++k)
                __builtin_nontemporal_store(z, (f4*)(out + orow + k * 256 + lane * 4));
            continue;
        }

        int start = widx[(size_t)word * 2 + 0];
        int end   = widx[(size_t)word * 2 + 1];
        float inv = 1.0f / (float)(end - start + 1);
        int ce = end >> LOG2_CS;
        const float* Le = L  + ((size_t)b * S + end) * H;
        const float* Ce = CT + ((size_t)b * NC + ce) * H;
        bool has_s = (start > 0);
        const float* Ls = Le; const float* Cs = Ce;
        if (has_s) {
            int sm = start - 1, cs = sm >> LOG2_CS;
            Ls = L  + ((size_t)b * S + sm) * H;
            Cs = CT + ((size_t)b * NC + cs) * H;
        }

#pragma unroll
        for (int k = 0; k < 4; ++k) {
            int off = k * 256 + lane * 4;
            f4 e  = *(const f4*)(Le + off);
            f4 ct = *(const f4*)(Ce + off);
            f4 ssum = e + ct;
            if (has_s) {
                f4 s4 = *(const f4*)(Ls + off);
                f4 c4 = *(const f4*)(Cs + off);
                ssum -= s4 + c4;
            }
            f4 o = ssum * inv;
            __builtin_nontemporal_store(o, (f4*)(out + orow + off));
        }
    }
}

// ---------------------------------------------------------------------------
// Fallback: direct summation if workspace is too small. Correct but slow.
// ---------------------------------------------------------------------------
__global__ void k_direct(const float* __restrict__ hs, const int* __restrict__ widx,
                         const int* __restrict__ mwl, float* __restrict__ out,
                         float* __restrict__ mask) {
    int w = blockIdx.x % W;
    int b = blockIdx.x / W;
    int t = threadIdx.x;
    bool valid = (w < mwl[b]);
    size_t orow = ((size_t)b * W + w) * H;
    if (t == 0) mask[(size_t)b * W + w] = valid ? 1.0f : 0.0f;

    f4 acc = {0.f, 0.f, 0.f, 0.f};
    if (valid) {
        int start = widx[((size_t)b * W + w) * 2 + 0];
        int end   = widx[((size_t)b * W + w) * 2 + 1];
        float inv = 1.0f / (float)(end - start + 1);
        for (int s = start; s <= end; ++s) {
            f4 v = *(const f4*)(hs + ((size_t)b * S + s) * H + (size_t)t * 4);
            acc += v;
        }
        acc *= inv;
    }
    *(f4*)(out + orow + (size_t)t * 4) = acc;
}

extern "C" void kernel_launch(void* const* d_in, const int* in_sizes, int n_in,
                              void* d_out, int out_size, void* d_ws, size_t ws_size,
                              hipStream_t stream) {
    const float* hs  = (const float*)d_in[0];
    const int*  widx = (const int*)d_in[1];
    const int*  mwl  = (const int*)d_in[2];
    float* out  = (float*)d_out;
    float* mask = out + (size_t)B * W * H;   // masks follow embeddings, flat

    const size_t Lbytes  = (size_t)B * S * H * sizeof(float);      // 256 MiB
    const size_t CTbytes = (size_t)B * NC * H * sizeof(float);     // 8 MiB

    if (ws_size >= Lbytes + CTbytes) {
        float* L  = (float*)d_ws;
        float* CT = (float*)((char*)d_ws + Lbytes);

        hipLaunchKernelGGL(k_prefix, dim3(B * NC),        dim3(256), 0, stream,
                           hs, widx, mwl, L, CT);
        hipLaunchKernelGGL(k_coarse, dim3(B * (H / 256)), dim3(256), 0, stream, CT);
        hipLaunchKernelGGL(k_gather, dim3(B * W / 8),     dim3(256), 0, stream,
                           L, CT, widx, mwl, out, mask);
    } else {
        hipLaunchKernelGGL(k_direct, dim3(B * W), dim3(256), 0, stream, hs, widx, mwl, out, mask);
    }
}

// Round 9
// 97.101 us; speedup vs baseline: 1.0469x; 1.0323x over previous
//
#include <hip/hip_runtime.h>

typedef float f4 __attribute__((ext_vector_type(4)));

static constexpr int B = 16, S = 4096, H = 1024, W = 1024;
static constexpr int NC = 128;           // number of S-chunks
static constexpr int CS = S / NC;        // 32 rows per chunk
static constexpr int LOG2_CS = 5;

// ---------------------------------------------------------------------------
// Kernel 1: chunk-local inclusive prefix along S with INLINE boundary-mask
// derivation (3 dispatches total — proven optimum, round 6: 97.2 us).
// Stores ONLY flagged rows of L; chunk totals stored densely to CT.
// grid = B*NC = 2048 blocks (8/CU, 32 waves/CU). 256 thr x f4 covers H=1024.
// ---------------------------------------------------------------------------
__global__ void __launch_bounds__(256)
k_prefix(const float* __restrict__ hs, const int* __restrict__ widx,
         const int* __restrict__ mwl, float* __restrict__ L,
         float* __restrict__ CT) {
    const int c = blockIdx.x % NC;
    const int b = blockIdx.x / NC;
    const int t = threadIdx.x;

    // --- derive this chunk's 32-bit boundary mask from widx ---
    __shared__ unsigned sbw;
    if (t == 0) sbw = 0u;
    __syncthreads();
    const int nv = mwl[b];
    const int lo = c * CS;
    unsigned mybits = 0u;
#pragma unroll
    for (int w = t; w < W; w += 256) {
        if (w < nv) {
            int2 se = *(const int2*)(widx + ((size_t)b * W + w) * 2);
            int e  = se.y - lo;
            int sm = se.x - 1 - lo;
            if ((unsigned)e  < (unsigned)CS) mybits |= 1u << e;
            if ((unsigned)sm < (unsigned)CS) mybits |= 1u << sm;
        }
    }
    if (mybits) atomicOr(&sbw, mybits);
    __syncthreads();
    const unsigned bw = sbw;

    // --- streaming scan: NT loads of hs, sparse plain stores of L ---
    const int col = t * 4;
    size_t rowbase = ((size_t)b * S + (size_t)lo) * H + col;
    f4 acc = {0.f, 0.f, 0.f, 0.f};
#pragma unroll 8
    for (int s = 0; s < CS; ++s) {
        f4 v = __builtin_nontemporal_load((const f4*)(hs + rowbase + (size_t)s * H));
        acc += v;
        if ((bw >> s) & 1u)
            *(f4*)(L + rowbase + (size_t)s * H) = acc;
    }
    *(f4*)(CT + ((size_t)b * NC + c) * H + col) = acc;
}

// ---------------------------------------------------------------------------
// Kernel 2: in-place exclusive scan of chunk totals along c.
// grid = B*(H/256) = 64 blocks.
// ---------------------------------------------------------------------------
__global__ void __launch_bounds__(256)
k_coarse(float* __restrict__ CT) {
    int hq = blockIdx.x % (H / 256);
    int b  = blockIdx.x / (H / 256);
    int h  = hq * 256 + threadIdx.x;
    float acc = 0.f;
#pragma unroll 8
    for (int c = 0; c < NC; ++c) {
        size_t idx = ((size_t)b * NC + c) * H + h;
        float v = CT[idx];
        CT[idx] = acc;
        acc += v;
    }
}

// ---------------------------------------------------------------------------
// Kernel 3: gather. One wave per word; 4 words per 256-thread block.
// sum(start..end) = (L[end]+CT[c_end]) - (L[start-1]+CT[c_sm]).
// NT stores for out (never re-read). All branches wave-uniform.
// ---------------------------------------------------------------------------
__global__ void __launch_bounds__(256)
k_gather(const float* __restrict__ L, const float* __restrict__ CT,
         const int* __restrict__ widx, const int* __restrict__ mwl,
         float* __restrict__ out, float* __restrict__ mask) {
    int t = threadIdx.x;
    int wid = t >> 6, lane = t & 63;
    int word = blockIdx.x * 4 + wid;
    int b = word / W, w = word % W;
    size_t orow = (size_t)word * H;

    bool valid = (w < mwl[b]);
    if (lane == 0) mask[word] = valid ? 1.0f : 0.0f;

    if (!valid) {
        f4 z = {0.f, 0.f, 0.f, 0.f};
#pragma unroll
        for (int k = 0; k < 4; ++k)
            __builtin_nontemporal_store(z, (f4*)(out + orow + k * 256 + lane * 4));
        return;
    }

    int start = widx[(size_t)word * 2 + 0];
    int end   = widx[(size_t)word * 2 + 1];
    float inv = 1.0f / (float)(end - start + 1);
    int ce = end >> LOG2_CS;
    const float* Le = L  + ((size_t)b * S + end) * H;
    const float* Ce = CT + ((size_t)b * NC + ce) * H;
    bool has_s = (start > 0);
    const float* Ls = Le; const float* Cs = Ce;
    if (has_s) {
        int sm = start - 1, cs = sm >> LOG2_CS;
        Ls = L  + ((size_t)b * S + sm) * H;
        Cs = CT + ((size_t)b * NC + cs) * H;
    }

#pragma unroll
    for (int k = 0; k < 4; ++k) {
        int off = k * 256 + lane * 4;
        f4 e  = *(const f4*)(Le + off);
        f4 ct = *(const f4*)(Ce + off);
        f4 ssum = e + ct;
        if (has_s) {
            f4 s4 = *(const f4*)(Ls + off);
            f4 c4 = *(const f4*)(Cs + off);
            ssum -= s4 + c4;
        }
        f4 o = ssum * inv;
        __builtin_nontemporal_store(o, (f4*)(out + orow + off));
    }
}

// ---------------------------------------------------------------------------
// Fallback: direct summation if workspace is too small. Correct but slow.
// ---------------------------------------------------------------------------
__global__ void k_direct(const float* __restrict__ hs, const int* __restrict__ widx,
                         const int* __restrict__ mwl, float* __restrict__ out,
                         float* __restrict__ mask) {
    int w = blockIdx.x % W;
    int b = blockIdx.x / W;
    int t = threadIdx.x;
    bool valid = (w < mwl[b]);
    size_t orow = ((size_t)b * W + w) * H;
    if (t == 0) mask[(size_t)b * W + w] = valid ? 1.0f : 0.0f;

    f4 acc = {0.f, 0.f, 0.f, 0.f};
    if (valid) {
        int start = widx[((size_t)b * W + w) * 2 + 0];
        int end   = widx[((size_t)b * W + w) * 2 + 1];
        float inv = 1.0f / (float)(end - start + 1);
        for (int s = start; s <= end; ++s) {
            f4 v = *(const f4*)(hs + ((size_t)b * S + s) * H + (size_t)t * 4);
            acc += v;
        }
        acc *= inv;
    }
    *(f4*)(out + orow + (size_t)t * 4) = acc;
}

extern "C" void kernel_launch(void* const* d_in, const int* in_sizes, int n_in,
                              void* d_out, int out_size, void* d_ws, size_t ws_size,
                              hipStream_t stream) {
    const float* hs  = (const float*)d_in[0];
    const int*  widx = (const int*)d_in[1];
    const int*  mwl  = (const int*)d_in[2];
    float* out  = (float*)d_out;
    float* mask = out + (size_t)B * W * H;   // masks follow embeddings, flat

    const size_t Lbytes  = (size_t)B * S * H * sizeof(float);      // 256 MiB
    const size_t CTbytes = (size_t)B * NC * H * sizeof(float);     // 8 MiB

    if (ws_size >= Lbytes + CTbytes) {
        float* L  = (float*)d_ws;
        float* CT = (float*)((char*)d_ws + Lbytes);

        hipLaunchKernelGGL(k_prefix, dim3(B * NC),        dim3(256), 0, stream,
                           hs, widx, mwl, L, CT);
        hipLaunchKernelGGL(k_coarse, dim3(B * (H / 256)), dim3(256), 0, stream, CT);
        hipLaunchKernelGGL(k_gather, dim3(B * W / 4),     dim3(256), 0, stream,
                           L, CT, widx, mwl, out, mask);
    } else {
        hipLaunchKernelGGL(k_direct, dim3(B * W), dim3(256), 0, stream, hs, widx, mwl, out, mask);
    }
}